// Round 3
// baseline (8818.192 us; speedup 1.0000x reference)
//
#include <hip/hip_runtime.h>
#include <hip/hip_bf16.h>

#define N_NODES 16384
#define KNBR 10

// async global->LDS, 16B per lane; LDS dest must be wave-uniform base (lane*16 implicit)
__device__ __forceinline__ void gload_lds16(const float* g, void* l) {
    __builtin_amdgcn_global_load_lds((const __attribute__((address_space(1))) void*)g,
                                     (__attribute__((address_space(3))) void*)l,
                                     16, 0, 0);
}

// ---------------------------------------------------------------------------
// K1: per-modality embeds -> xcat [N,192]  (ReLU(Linear))
// ---------------------------------------------------------------------------
__global__ __launch_bounds__(256) void embed_kernel(
        const float* __restrict__ nf, const float* __restrict__ rf,
        const float* __restrict__ tf,
        const float* __restrict__ Wb, const float* __restrict__ bb,
        const float* __restrict__ Wr, const float* __restrict__ br,
        const float* __restrict__ Wt, const float* __restrict__ bt,
        float* __restrict__ xcat, int n) {
    int t = blockIdx.x * blockDim.x + threadIdx.x;
    if (t >= n * 192) return;
    int i = t / 192, o = t % 192;
    float acc;
    if (o < 64) {
        acc = bb[o];
        #pragma unroll
        for (int d = 0; d < 8; ++d) acc = fmaf(nf[i * 8 + d], Wb[d * 64 + o], acc);
    } else if (o < 128) {
        int oo = o - 64;
        acc = br[oo];
        #pragma unroll 8
        for (int d = 0; d < 64; ++d) acc = fmaf(rf[i * 64 + d], Wr[d * 64 + oo], acc);
    } else {
        int oo = o - 128;
        acc = bt[oo];
        #pragma unroll 8
        for (int d = 0; d < 64; ++d) acc = fmaf(tf[i * 64 + d], Wt[d * 64 + oo], acc);
    }
    xcat[t] = fmaxf(acc, 0.0f);
}

// ---------------------------------------------------------------------------
// K2: fusion -> h [N,128]  (LeakyReLU(Linear))
// ---------------------------------------------------------------------------
__global__ __launch_bounds__(256) void fuse_kernel(
        const float* __restrict__ xcat, const float* __restrict__ Wf,
        const float* __restrict__ bf, float* __restrict__ h, int n) {
    int t = blockIdx.x * blockDim.x + threadIdx.x;
    if (t >= n * 128) return;
    int i = t >> 7, o = t & 127;
    float acc = bf[o];
    const float* xr = xcat + (size_t)i * 192;
    #pragma unroll 8
    for (int d = 0; d < 192; ++d) acc = fmaf(xr[d], Wf[d * 128 + o], acc);
    h[t] = acc > 0.f ? acc : 0.01f * acc;
}

// ---------------------------------------------------------------------------
// K3: row squared-norms (one wave per row)
// ---------------------------------------------------------------------------
__global__ void sqnorm_kernel(const float* __restrict__ x, float* __restrict__ sq,
                              int n, int D) {
    int w = (blockIdx.x * blockDim.x + threadIdx.x) >> 6;
    int lane = threadIdx.x & 63;
    if (w >= n) return;
    float s = 0.f;
    for (int d = lane; d < D; d += 64) {
        float v = x[(size_t)w * D + d];
        s = fmaf(v, v, s);
    }
    #pragma unroll
    for (int off = 32; off > 0; off >>= 1) s += __shfl_down(s, off);
    if (lane == 0) sq[w] = s;
}

// ---------------------------------------------------------------------------
// K4: fused pairwise-distance GEMM + per-row top-10 over a j-slice.
//   grid = (n/128) * 8 slices; block = 256 threads; tile 128x128; micro 8x8.
//   d staged in KC=32 chunks via global_load_lds (linear LDS dest, source
//   pre-swizzled so compute reads are XOR-deswizzled: av conflict-free
//   16-way bcast, bv 2-way).
//   LDS: union{ XiC[128][8]f4 + XjC[128][8]f4 (32KB) | Dt[128][65] (33.3KB) }
//        + sqj[128] -> 33.8KB total => 4 blocks/CU by LDS, 3 by VGPR cap.
//   Scan: thread tid<128 owns query row; strict-< streaming insert in
//   ascending-j order == jax.lax.top_k low-index tie-break. Emits per-slice
//   (dist,idx) top-10 partials, merged by knn_merge_kernel.
// ---------------------------------------------------------------------------
template <int D>
__global__ __launch_bounds__(256, 3) void knn_kernel(const float* __restrict__ x,
                                                     const float* __restrict__ sq,
                                                     float* __restrict__ pd,
                                                     int* __restrict__ pi, int n) {
    constexpr int TM = 128, TJ = 128, KC = 32, LD4 = KC / 4;  // 8 f4 per row-chunk
    constexpr int NCH = D / KC;
    constexpr int PSL = 8;

    __shared__ __align__(16) char smem[TM * 65 * 4 + TJ * 4];   // 33280 + 512
    float4* XiC = (float4*)smem;                    // [TM][LD4]
    float4* XjC = ((float4*)smem) + TM * LD4;       // [TJ][LD4]
    float*  Dt  = (float*)smem;                     // [TM][65]  (union)
    float*  sqj = (float*)(smem + TM * 65 * 4);     // [TJ]

    const int tid  = threadIdx.x;
    const int wv   = tid >> 6;
    const int lane = tid & 63;
    const int ty = tid >> 4, tx = tid & 15;
    const int mb = blockIdx.x >> 3, ps = blockIdx.x & 7;
    const int i0 = mb * TM;
    const int jsl = n >> 3;                 // 2048 cols per slice
    const int j0 = ps * jsl;

    // staging geometry: wave-issue w covers linear f4 fi=(wv*4+w)*64+lane;
    // LDS slot (row, fi&7) receives global f4 column (fi&7)^(row&7).
    int rowS[4], colS[4];
    #pragma unroll
    for (int w = 0; w < 4; ++w) {
        int fi = (wv * 4 + w) * 64 + lane;
        rowS[w] = fi >> 3;
        colS[w] = (fi & 7) ^ (rowS[w] & 7);
    }

    float bd[KNBR];
    int bi[KNBR];
    #pragma unroll
    for (int q = 0; q < KNBR; ++q) { bd[q] = 3.4e38f; bi[q] = 0; }
    const float my_sqi = (tid < TM) ? sq[i0 + tid] : 0.f;

    for (int jt = 0; jt < jsl; jt += TJ) {
        float acc[8][8];
        #pragma unroll
        for (int r = 0; r < 8; ++r)
            #pragma unroll
            for (int c = 0; c < 8; ++c) acc[r][c] = 0.f;

        for (int s = 0; s < NCH; ++s) {
            __syncthreads();  // prev scan / prev chunk compute done -> LDS reusable
            #pragma unroll
            for (int w = 0; w < 4; ++w)
                gload_lds16(x + (size_t)(i0 + rowS[w]) * D + s * KC + colS[w] * 4,
                            XiC + (wv * 4 + w) * 64);
            #pragma unroll
            for (int w = 0; w < 4; ++w)
                gload_lds16(x + (size_t)(j0 + jt + rowS[w]) * D + s * KC + colS[w] * 4,
                            XjC + (wv * 4 + w) * 64);
            if (s == 0 && tid < TJ) sqj[tid] = sq[j0 + jt + tid];
            __syncthreads();  // barrier drains vmcnt -> staged data visible

            #pragma unroll
            for (int d4 = 0; d4 < LD4; ++d4) {
                const int si = d4 ^ (ty & 7);   // rows ty+16r share (row&7)=ty&7
                const int sj = d4 ^ (tx & 7);
                float4 av[8];
                #pragma unroll
                for (int r = 0; r < 8; ++r) av[r] = XiC[(ty + 16 * r) * LD4 + si];
                #pragma unroll
                for (int c = 0; c < 8; ++c) {
                    float4 bv = XjC[(tx + 16 * c) * LD4 + sj];
                    #pragma unroll
                    for (int r = 0; r < 8; ++r) {
                        acc[r][c] = fmaf(av[r].x, bv.x, acc[r][c]);
                        acc[r][c] = fmaf(av[r].y, bv.y, acc[r][c]);
                        acc[r][c] = fmaf(av[r].z, bv.z, acc[r][c]);
                        acc[r][c] = fmaf(av[r].w, bv.w, acc[r][c]);
                    }
                }
            }
        }

        // dump + scan in two 64-col halves (Dt unioned over XiC/XjC)
        #pragma unroll
        for (int h = 0; h < 2; ++h) {
            __syncthreads();  // h=0: compute reads done; h=1: half-1 scan done
            #pragma unroll
            for (int r = 0; r < 8; ++r)
                #pragma unroll
                for (int c = 0; c < 4; ++c)
                    Dt[(ty + 16 * r) * 65 + tx + 16 * c] = acc[r][4 * h + c];
            __syncthreads();
            if (tid < TM) {
                const int ig = i0 + tid;
                const float* drow = Dt + tid * 65;
                const int jb = j0 + jt + 64 * h;
                for (int c2 = 0; c2 < 64; ++c2) {
                    int j = jb + c2;
                    float dist = my_sqi + sqj[64 * h + c2] - 2.0f * drow[c2];
                    if (dist < bd[KNBR - 1] && j != ig) {
                        bd[KNBR - 1] = dist;
                        bi[KNBR - 1] = j;
                        #pragma unroll
                        for (int q2 = KNBR - 2; q2 >= 0; --q2) {
                            if (bd[q2 + 1] < bd[q2]) {
                                float td = bd[q2]; bd[q2] = bd[q2 + 1]; bd[q2 + 1] = td;
                                int tj = bi[q2]; bi[q2] = bi[q2 + 1]; bi[q2 + 1] = tj;
                            }
                        }
                    }
                }
            }
        }
    }

    if (tid < TM) {
        size_t base = ((size_t)(i0 + tid) * PSL + ps) * KNBR;
        #pragma unroll
        for (int q = 0; q < KNBR; ++q) { pd[base + q] = bd[q]; pi[base + q] = bi[q]; }
    }
}

// ---------------------------------------------------------------------------
// K4b: merge 8 per-slice sorted top-10 partials -> final top-10 indices.
//   Slices processed in ascending-j order with strict-< insert => stable
//   low-index tie-break preserved globally.
// ---------------------------------------------------------------------------
__global__ __launch_bounds__(256) void knn_merge_kernel(const float* __restrict__ pd,
                                                        const int* __restrict__ pi,
                                                        int* __restrict__ idx, int n) {
    int row = blockIdx.x * blockDim.x + threadIdx.x;
    if (row >= n) return;
    float bd[KNBR];
    int bi[KNBR];
    #pragma unroll
    for (int q = 0; q < KNBR; ++q) { bd[q] = 3.4e38f; bi[q] = 0; }
    const float* prow = pd + (size_t)row * 8 * KNBR;
    const int*   irow = pi + (size_t)row * 8 * KNBR;
    for (int e = 0; e < 8 * KNBR; ++e) {
        float dist = prow[e];
        if (dist < bd[KNBR - 1]) {
            bd[KNBR - 1] = dist;
            bi[KNBR - 1] = irow[e];
            #pragma unroll
            for (int q2 = KNBR - 2; q2 >= 0; --q2) {
                if (bd[q2 + 1] < bd[q2]) {
                    float td = bd[q2]; bd[q2] = bd[q2 + 1]; bd[q2 + 1] = td;
                    int tj = bi[q2]; bi[q2] = bi[q2 + 1]; bi[q2 + 1] = tj;
                }
            }
        }
    }
    #pragma unroll
    for (int q = 0; q < KNBR; ++q) idx[(size_t)row * KNBR + q] = bi[q];
}

// ---------------------------------------------------------------------------
// K5: EdgeConv: out[i,o] = max_k leaky_relu( [x_i, x_j-x_i] @ W + b )
//   structure split: a_o = b_o + x_i . W_top[:,o] computed once per node.
//   block = 64 threads (thread = output channel o), NN=4 nodes per block.
//   xi/xd staged in LDS as float4; inner reads are same-address broadcast
//   ds_read_b128 (conflict-free), 4 d-values per read.
// ---------------------------------------------------------------------------
template <int D>
__global__ __launch_bounds__(64) void edgeconv_kernel(const float* __restrict__ x,
                                                      const int* __restrict__ idx,
                                                      const float* __restrict__ W,
                                                      const float* __restrict__ bias,
                                                      float* __restrict__ out, int n) {
    constexpr int NN = 4;
    constexpr int D4 = D / 4;
    const int base = blockIdx.x * NN;
    const int o = threadIdx.x;

    __shared__ float4 xi4[NN][D4];
    __shared__ float4 xd4[NN][KNBR][D4];
    float* xi = (float*)xi4;   // [NN][D] linear view
    float* xd = (float*)xd4;   // [NN][KNBR][D] linear view

    for (int nn = 0; nn < NN; ++nn)
        for (int d = o; d < D; d += 64) xi[nn * D + d] = x[(size_t)(base + nn) * D + d];
    __syncthreads();
    for (int nn = 0; nn < NN; ++nn)
        for (int k = 0; k < KNBR; ++k) {
            int j = idx[(size_t)(base + nn) * KNBR + k];
            for (int d = o; d < D; d += 64)
                xd[(nn * KNBR + k) * D + d] = x[(size_t)j * D + d] - xi[nn * D + d];
        }
    __syncthreads();

    float a[NN];
    float bo = bias[o];
    #pragma unroll
    for (int nn = 0; nn < NN; ++nn) a[nn] = bo;
    for (int d4 = 0; d4 < D4; ++d4) {
        float4 xv[NN];
        #pragma unroll
        for (int nn = 0; nn < NN; ++nn) xv[nn] = xi4[nn][d4];  // broadcast read
        #pragma unroll
        for (int e = 0; e < 4; ++e) {
            float w = W[(d4 * 4 + e) * 64 + o];
            #pragma unroll
            for (int nn = 0; nn < NN; ++nn)
                a[nn] = fmaf(((const float*)&xv[nn])[e], w, a[nn]);
        }
    }

    float m[NN];
    #pragma unroll
    for (int nn = 0; nn < NN; ++nn) m[nn] = -3.4e38f;
    for (int k = 0; k < KNBR; ++k) {
        float acc[NN];
        #pragma unroll
        for (int nn = 0; nn < NN; ++nn) acc[nn] = a[nn];
        for (int d4 = 0; d4 < D4; ++d4) {
            float4 xv[NN];
            #pragma unroll
            for (int nn = 0; nn < NN; ++nn) xv[nn] = xd4[nn][k][d4];  // broadcast read
            #pragma unroll
            for (int e = 0; e < 4; ++e) {
                float w = W[(D + d4 * 4 + e) * 64 + o];
                #pragma unroll
                for (int nn = 0; nn < NN; ++nn)
                    acc[nn] = fmaf(((const float*)&xv[nn])[e], w, acc[nn]);
            }
        }
        #pragma unroll
        for (int nn = 0; nn < NN; ++nn) {
            float v = acc[nn] > 0.f ? acc[nn] : 0.01f * acc[nn];
            m[nn] = fmaxf(m[nn], v);
        }
    }
    for (int nn = 0; nn < NN; ++nn) out[(size_t)(base + nn) * 64 + o] = m[nn];
}

// ---------------------------------------------------------------------------
// K6: classifier logits = [g1,g2] @ Wc + bc
// ---------------------------------------------------------------------------
__global__ void classifier_kernel(const float* __restrict__ g1, const float* __restrict__ g2,
                                  const float* __restrict__ Wc, const float* __restrict__ bc,
                                  float* __restrict__ out, int n) {
    int t = blockIdx.x * blockDim.x + threadIdx.x;
    if (t >= n * 16) return;
    int i = t >> 4, c = t & 15;
    float acc = bc[c];
    #pragma unroll 8
    for (int d = 0; d < 64; ++d) acc = fmaf(g1[(size_t)i * 64 + d], Wc[d * 16 + c], acc);
    #pragma unroll 8
    for (int d = 0; d < 64; ++d) acc = fmaf(g2[(size_t)i * 64 + d], Wc[(64 + d) * 16 + c], acc);
    out[t] = acc;
}

// ---------------------------------------------------------------------------
extern "C" void kernel_launch(void* const* d_in, const int* in_sizes, int n_in,
                              void* d_out, int out_size, void* d_ws, size_t ws_size,
                              hipStream_t stream) {
    const int n = N_NODES;
    const float* node_feat = (const float*)d_in[0];
    const float* rf_feat   = (const float*)d_in[1];
    const float* txp_feat  = (const float*)d_in[2];
    const float* Wb = (const float*)d_in[3];
    const float* bb = (const float*)d_in[4];
    const float* Wr = (const float*)d_in[5];
    const float* br = (const float*)d_in[6];
    const float* Wt = (const float*)d_in[7];
    const float* bt = (const float*)d_in[8];
    const float* Wf = (const float*)d_in[9];
    const float* bf = (const float*)d_in[10];
    const float* We1 = (const float*)d_in[11];
    const float* be1 = (const float*)d_in[12];
    const float* We2 = (const float*)d_in[13];
    const float* be2 = (const float*)d_in[14];
    const float* Wc = (const float*)d_in[15];
    const float* bc = (const float*)d_in[16];

    // workspace layout (fp32): xcat | h | sq | g1 | g2 | idx
    // knn partials (pd/pi: n*80 floats/ints each = n*160 < n*192) alias xcat,
    // which is dead after fuse_kernel.
    float* xcat = (float*)d_ws;
    float* h    = xcat + (size_t)n * 192;
    float* sqv  = h + (size_t)n * 128;
    float* g1   = sqv + n;
    float* g2   = g1 + (size_t)n * 64;
    int*   idx  = (int*)(g2 + (size_t)n * 64);
    float* pd   = xcat;
    int*   pi   = (int*)(xcat + (size_t)n * 80);

    embed_kernel<<<(n * 192 + 255) / 256, 256, 0, stream>>>(
        node_feat, rf_feat, txp_feat, Wb, bb, Wr, br, Wt, bt, xcat, n);
    fuse_kernel<<<(n * 128 + 255) / 256, 256, 0, stream>>>(xcat, Wf, bf, h, n);

    // layer 1: KNN on h (D=128) + EdgeConv -> g1
    sqnorm_kernel<<<(n * 64 + 255) / 256, 256, 0, stream>>>(h, sqv, n, 128);
    knn_kernel<128><<<(n / 128) * 8, 256, 0, stream>>>(h, sqv, pd, pi, n);
    knn_merge_kernel<<<(n + 255) / 256, 256, 0, stream>>>(pd, pi, idx, n);
    edgeconv_kernel<128><<<n / 4, 64, 0, stream>>>(h, idx, We1, be1, g1, n);

    // layer 2: KNN on g1 (D=64) + EdgeConv -> g2
    sqnorm_kernel<<<(n * 64 + 255) / 256, 256, 0, stream>>>(g1, sqv, n, 64);
    knn_kernel<64><<<(n / 128) * 8, 256, 0, stream>>>(g1, sqv, pd, pi, n);
    knn_merge_kernel<<<(n + 255) / 256, 256, 0, stream>>>(pd, pi, idx, n);
    edgeconv_kernel<64><<<n / 4, 64, 0, stream>>>(g1, idx, We2, be2, g2, n);

    classifier_kernel<<<(n * 16 + 255) / 256, 256, 0, stream>>>(g1, g2, Wc, bc,
                                                                (float*)d_out, n);
}

// Round 4
// 3386.966 us; speedup vs baseline: 2.6036x; 2.6036x over previous
//
#include <hip/hip_runtime.h>
#include <hip/hip_bf16.h>

#define N_NODES 16384
#define KNBR 10

// async global->LDS, 16B per lane; LDS dest must be wave-uniform base (lane*16 implicit)
__device__ __forceinline__ void gload_lds16(const float* g, void* l) {
    __builtin_amdgcn_global_load_lds((const __attribute__((address_space(1))) void*)g,
                                     (__attribute__((address_space(3))) void*)l,
                                     16, 0, 0);
}

// ---------------------------------------------------------------------------
// K1: per-modality embeds -> xcat [N,192]  (ReLU(Linear))
// ---------------------------------------------------------------------------
__global__ __launch_bounds__(256) void embed_kernel(
        const float* __restrict__ nf, const float* __restrict__ rf,
        const float* __restrict__ tf,
        const float* __restrict__ Wb, const float* __restrict__ bb,
        const float* __restrict__ Wr, const float* __restrict__ br,
        const float* __restrict__ Wt, const float* __restrict__ bt,
        float* __restrict__ xcat, int n) {
    int t = blockIdx.x * blockDim.x + threadIdx.x;
    if (t >= n * 192) return;
    int i = t / 192, o = t % 192;
    float acc;
    if (o < 64) {
        acc = bb[o];
        #pragma unroll
        for (int d = 0; d < 8; ++d) acc = fmaf(nf[i * 8 + d], Wb[d * 64 + o], acc);
    } else if (o < 128) {
        int oo = o - 64;
        acc = br[oo];
        #pragma unroll 8
        for (int d = 0; d < 64; ++d) acc = fmaf(rf[i * 64 + d], Wr[d * 64 + oo], acc);
    } else {
        int oo = o - 128;
        acc = bt[oo];
        #pragma unroll 8
        for (int d = 0; d < 64; ++d) acc = fmaf(tf[i * 64 + d], Wt[d * 64 + oo], acc);
    }
    xcat[t] = fmaxf(acc, 0.0f);
}

// ---------------------------------------------------------------------------
// K2: fusion -> h [N,128]  (LeakyReLU(Linear))
// ---------------------------------------------------------------------------
__global__ __launch_bounds__(256) void fuse_kernel(
        const float* __restrict__ xcat, const float* __restrict__ Wf,
        const float* __restrict__ bf, float* __restrict__ h, int n) {
    int t = blockIdx.x * blockDim.x + threadIdx.x;
    if (t >= n * 128) return;
    int i = t >> 7, o = t & 127;
    float acc = bf[o];
    const float* xr = xcat + (size_t)i * 192;
    #pragma unroll 8
    for (int d = 0; d < 192; ++d) acc = fmaf(xr[d], Wf[d * 128 + o], acc);
    h[t] = acc > 0.f ? acc : 0.01f * acc;
}

// ---------------------------------------------------------------------------
// K3: row squared-norms (one wave per row)
// ---------------------------------------------------------------------------
__global__ void sqnorm_kernel(const float* __restrict__ x, float* __restrict__ sq,
                              int n, int D) {
    int w = (blockIdx.x * blockDim.x + threadIdx.x) >> 6;
    int lane = threadIdx.x & 63;
    if (w >= n) return;
    float s = 0.f;
    for (int d = lane; d < D; d += 64) {
        float v = x[(size_t)w * D + d];
        s = fmaf(v, v, s);
    }
    #pragma unroll
    for (int off = 32; off > 0; off >>= 1) s += __shfl_down(s, off);
    if (lane == 0) sq[w] = s;
}

// ---------------------------------------------------------------------------
// K4: fused pairwise-distance GEMM + per-row top-10 over a j-slice.
//   grid = (n/128) * 8 slices; block = 256 threads; tile 128x128; micro 8x8.
//   d staged in KC=32 chunks via global_load_lds (linear LDS dest, source
//   pre-swizzled so compute reads are XOR-deswizzled: av conflict-free
//   16-way bcast, bv 2-way).
//   LDS: union{ XiC[128][8]f4 + XjC[128][8]f4 (32KB) | Dt[128][65] (33.3KB) }
//        + sqj[128] -> 33.8KB total.
//   __launch_bounds__(256,2): VGPR budget 256 -- R3's (256,3) capped the
//   budget at ~170 and spilled acc[8][8] to scratch (WRITE_SIZE 8.7 GB).
//   Scan: thread tid<128 owns query row; strict-< streaming insert in
//   ascending-j order == jax.lax.top_k low-index tie-break. Emits per-slice
//   (dist,idx) top-10 partials, merged by knn_merge_kernel.
// ---------------------------------------------------------------------------
template <int D>
__global__ __launch_bounds__(256, 2) void knn_kernel(const float* __restrict__ x,
                                                     const float* __restrict__ sq,
                                                     float* __restrict__ pd,
                                                     int* __restrict__ pi, int n) {
    constexpr int TM = 128, TJ = 128, KC = 32, LD4 = KC / 4;  // 8 f4 per row-chunk
    constexpr int NCH = D / KC;
    constexpr int PSL = 8;

    __shared__ __align__(16) char smem[TM * 65 * 4 + TJ * 4];   // 33280 + 512
    float4* XiC = (float4*)smem;                    // [TM][LD4]
    float4* XjC = ((float4*)smem) + TM * LD4;       // [TJ][LD4]
    float*  Dt  = (float*)smem;                     // [TM][65]  (union)
    float*  sqj = (float*)(smem + TM * 65 * 4);     // [TJ]

    const int tid  = threadIdx.x;
    const int wv   = tid >> 6;
    const int lane = tid & 63;
    const int ty = tid >> 4, tx = tid & 15;
    const int mb = blockIdx.x >> 3, ps = blockIdx.x & 7;
    const int i0 = mb * TM;
    const int jsl = n >> 3;                 // 2048 cols per slice
    const int j0 = ps * jsl;

    // staging geometry: wave-issue w covers linear f4 fi=(wv*4+w)*64+lane;
    // LDS slot (row, fi&7) receives global f4 column (fi&7)^(row&7).
    int rowS[4], colS[4];
    #pragma unroll
    for (int w = 0; w < 4; ++w) {
        int fi = (wv * 4 + w) * 64 + lane;
        rowS[w] = fi >> 3;
        colS[w] = (fi & 7) ^ (rowS[w] & 7);
    }

    float bd[KNBR];
    int bi[KNBR];
    #pragma unroll
    for (int q = 0; q < KNBR; ++q) { bd[q] = 3.4e38f; bi[q] = 0; }
    const float my_sqi = (tid < TM) ? sq[i0 + tid] : 0.f;

    for (int jt = 0; jt < jsl; jt += TJ) {
        float acc[8][8];
        #pragma unroll
        for (int r = 0; r < 8; ++r)
            #pragma unroll
            for (int c = 0; c < 8; ++c) acc[r][c] = 0.f;

        for (int s = 0; s < NCH; ++s) {
            __syncthreads();  // prev scan / prev chunk compute done -> LDS reusable
            #pragma unroll
            for (int w = 0; w < 4; ++w)
                gload_lds16(x + (size_t)(i0 + rowS[w]) * D + s * KC + colS[w] * 4,
                            XiC + (wv * 4 + w) * 64);
            #pragma unroll
            for (int w = 0; w < 4; ++w)
                gload_lds16(x + (size_t)(j0 + jt + rowS[w]) * D + s * KC + colS[w] * 4,
                            XjC + (wv * 4 + w) * 64);
            if (s == 0 && tid < TJ) sqj[tid] = sq[j0 + jt + tid];
            __syncthreads();  // barrier drains vmcnt -> staged data visible

            #pragma unroll
            for (int d4 = 0; d4 < LD4; ++d4) {
                const int si = d4 ^ (ty & 7);   // rows ty+16r share (row&7)=ty&7
                const int sj = d4 ^ (tx & 7);
                float4 av[8];
                #pragma unroll
                for (int r = 0; r < 8; ++r) av[r] = XiC[(ty + 16 * r) * LD4 + si];
                #pragma unroll
                for (int c = 0; c < 8; ++c) {
                    float4 bv = XjC[(tx + 16 * c) * LD4 + sj];
                    #pragma unroll
                    for (int r = 0; r < 8; ++r) {
                        acc[r][c] = fmaf(av[r].x, bv.x, acc[r][c]);
                        acc[r][c] = fmaf(av[r].y, bv.y, acc[r][c]);
                        acc[r][c] = fmaf(av[r].z, bv.z, acc[r][c]);
                        acc[r][c] = fmaf(av[r].w, bv.w, acc[r][c]);
                    }
                }
            }
        }

        // dump + scan in two 64-col halves (Dt unioned over XiC/XjC)
        #pragma unroll
        for (int h = 0; h < 2; ++h) {
            __syncthreads();  // h=0: compute reads done; h=1: half-1 scan done
            #pragma unroll
            for (int r = 0; r < 8; ++r)
                #pragma unroll
                for (int c = 0; c < 4; ++c)
                    Dt[(ty + 16 * r) * 65 + tx + 16 * c] = acc[r][4 * h + c];
            __syncthreads();
            if (tid < TM) {
                const int ig = i0 + tid;
                const float* drow = Dt + tid * 65;
                const int jb = j0 + jt + 64 * h;
                for (int c2 = 0; c2 < 64; ++c2) {
                    int j = jb + c2;
                    float dist = my_sqi + sqj[64 * h + c2] - 2.0f * drow[c2];
                    if (dist < bd[KNBR - 1] && j != ig) {
                        bd[KNBR - 1] = dist;
                        bi[KNBR - 1] = j;
                        #pragma unroll
                        for (int q2 = KNBR - 2; q2 >= 0; --q2) {
                            if (bd[q2 + 1] < bd[q2]) {
                                float td = bd[q2]; bd[q2] = bd[q2 + 1]; bd[q2 + 1] = td;
                                int tj = bi[q2]; bi[q2] = bi[q2 + 1]; bi[q2 + 1] = tj;
                            }
                        }
                    }
                }
            }
        }
    }

    if (tid < TM) {
        size_t base = ((size_t)(i0 + tid) * PSL + ps) * KNBR;
        #pragma unroll
        for (int q = 0; q < KNBR; ++q) { pd[base + q] = bd[q]; pi[base + q] = bi[q]; }
    }
}

// ---------------------------------------------------------------------------
// K4b: merge 8 per-slice sorted top-10 partials -> final top-10 indices.
//   Slices processed in ascending-j order with strict-< insert => stable
//   low-index tie-break preserved globally.
// ---------------------------------------------------------------------------
__global__ __launch_bounds__(256) void knn_merge_kernel(const float* __restrict__ pd,
                                                        const int* __restrict__ pi,
                                                        int* __restrict__ idx, int n) {
    int row = blockIdx.x * blockDim.x + threadIdx.x;
    if (row >= n) return;
    float bd[KNBR];
    int bi[KNBR];
    #pragma unroll
    for (int q = 0; q < KNBR; ++q) { bd[q] = 3.4e38f; bi[q] = 0; }
    const float* prow = pd + (size_t)row * 8 * KNBR;
    const int*   irow = pi + (size_t)row * 8 * KNBR;
    for (int e = 0; e < 8 * KNBR; ++e) {
        float dist = prow[e];
        if (dist < bd[KNBR - 1]) {
            bd[KNBR - 1] = dist;
            bi[KNBR - 1] = irow[e];
            #pragma unroll
            for (int q2 = KNBR - 2; q2 >= 0; --q2) {
                if (bd[q2 + 1] < bd[q2]) {
                    float td = bd[q2]; bd[q2] = bd[q2 + 1]; bd[q2 + 1] = td;
                    int tj = bi[q2]; bi[q2] = bi[q2 + 1]; bi[q2 + 1] = tj;
                }
            }
        }
    }
    #pragma unroll
    for (int q = 0; q < KNBR; ++q) idx[(size_t)row * KNBR + q] = bi[q];
}

// ---------------------------------------------------------------------------
// K5: EdgeConv: out[i,o] = max_k leaky_relu( [x_i, x_j-x_i] @ W + b )
//   structure split: a_o = b_o + x_i . W_top[:,o] computed once per node.
//   block = 64 threads (thread = output channel o), NN=4 nodes per block.
//   xi/xd staged in LDS as float4; inner reads are same-address broadcast
//   ds_read_b128 (conflict-free), 4 d-values per read.
// ---------------------------------------------------------------------------
template <int D>
__global__ __launch_bounds__(64) void edgeconv_kernel(const float* __restrict__ x,
                                                      const int* __restrict__ idx,
                                                      const float* __restrict__ W,
                                                      const float* __restrict__ bias,
                                                      float* __restrict__ out, int n) {
    constexpr int NN = 4;
    constexpr int D4 = D / 4;
    const int base = blockIdx.x * NN;
    const int o = threadIdx.x;

    __shared__ float4 xi4[NN][D4];
    __shared__ float4 xd4[NN][KNBR][D4];
    float* xi = (float*)xi4;   // [NN][D] linear view
    float* xd = (float*)xd4;   // [NN][KNBR][D] linear view

    for (int nn = 0; nn < NN; ++nn)
        for (int d = o; d < D; d += 64) xi[nn * D + d] = x[(size_t)(base + nn) * D + d];
    __syncthreads();
    for (int nn = 0; nn < NN; ++nn)
        for (int k = 0; k < KNBR; ++k) {
            int j = idx[(size_t)(base + nn) * KNBR + k];
            for (int d = o; d < D; d += 64)
                xd[(nn * KNBR + k) * D + d] = x[(size_t)j * D + d] - xi[nn * D + d];
        }
    __syncthreads();

    float a[NN];
    float bo = bias[o];
    #pragma unroll
    for (int nn = 0; nn < NN; ++nn) a[nn] = bo;
    for (int d4 = 0; d4 < D4; ++d4) {
        float4 xv[NN];
        #pragma unroll
        for (int nn = 0; nn < NN; ++nn) xv[nn] = xi4[nn][d4];  // broadcast read
        #pragma unroll
        for (int e = 0; e < 4; ++e) {
            float w = W[(d4 * 4 + e) * 64 + o];
            #pragma unroll
            for (int nn = 0; nn < NN; ++nn)
                a[nn] = fmaf(((const float*)&xv[nn])[e], w, a[nn]);
        }
    }

    float m[NN];
    #pragma unroll
    for (int nn = 0; nn < NN; ++nn) m[nn] = -3.4e38f;
    for (int k = 0; k < KNBR; ++k) {
        float acc[NN];
        #pragma unroll
        for (int nn = 0; nn < NN; ++nn) acc[nn] = a[nn];
        for (int d4 = 0; d4 < D4; ++d4) {
            float4 xv[NN];
            #pragma unroll
            for (int nn = 0; nn < NN; ++nn) xv[nn] = xd4[nn][k][d4];  // broadcast read
            #pragma unroll
            for (int e = 0; e < 4; ++e) {
                float w = W[(D + d4 * 4 + e) * 64 + o];
                #pragma unroll
                for (int nn = 0; nn < NN; ++nn)
                    acc[nn] = fmaf(((const float*)&xv[nn])[e], w, acc[nn]);
            }
        }
        #pragma unroll
        for (int nn = 0; nn < NN; ++nn) {
            float v = acc[nn] > 0.f ? acc[nn] : 0.01f * acc[nn];
            m[nn] = fmaxf(m[nn], v);
        }
    }
    for (int nn = 0; nn < NN; ++nn) out[(size_t)(base + nn) * 64 + o] = m[nn];
}

// ---------------------------------------------------------------------------
// K6: classifier logits = [g1,g2] @ Wc + bc
// ---------------------------------------------------------------------------
__global__ void classifier_kernel(const float* __restrict__ g1, const float* __restrict__ g2,
                                  const float* __restrict__ Wc, const float* __restrict__ bc,
                                  float* __restrict__ out, int n) {
    int t = blockIdx.x * blockDim.x + threadIdx.x;
    if (t >= n * 16) return;
    int i = t >> 4, c = t & 15;
    float acc = bc[c];
    #pragma unroll 8
    for (int d = 0; d < 64; ++d) acc = fmaf(g1[(size_t)i * 64 + d], Wc[d * 16 + c], acc);
    #pragma unroll 8
    for (int d = 0; d < 64; ++d) acc = fmaf(g2[(size_t)i * 64 + d], Wc[(64 + d) * 16 + c], acc);
    out[t] = acc;
}

// ---------------------------------------------------------------------------
extern "C" void kernel_launch(void* const* d_in, const int* in_sizes, int n_in,
                              void* d_out, int out_size, void* d_ws, size_t ws_size,
                              hipStream_t stream) {
    const int n = N_NODES;
    const float* node_feat = (const float*)d_in[0];
    const float* rf_feat   = (const float*)d_in[1];
    const float* txp_feat  = (const float*)d_in[2];
    const float* Wb = (const float*)d_in[3];
    const float* bb = (const float*)d_in[4];
    const float* Wr = (const float*)d_in[5];
    const float* br = (const float*)d_in[6];
    const float* Wt = (const float*)d_in[7];
    const float* bt = (const float*)d_in[8];
    const float* Wf = (const float*)d_in[9];
    const float* bf = (const float*)d_in[10];
    const float* We1 = (const float*)d_in[11];
    const float* be1 = (const float*)d_in[12];
    const float* We2 = (const float*)d_in[13];
    const float* be2 = (const float*)d_in[14];
    const float* Wc = (const float*)d_in[15];
    const float* bc = (const float*)d_in[16];

    // workspace layout (fp32): xcat | h | sq | g1 | g2 | idx
    // knn partials (pd/pi: n*80 floats/ints each = n*160 < n*192) alias xcat,
    // which is dead after fuse_kernel.
    float* xcat = (float*)d_ws;
    float* h    = xcat + (size_t)n * 192;
    float* sqv  = h + (size_t)n * 128;
    float* g1   = sqv + n;
    float* g2   = g1 + (size_t)n * 64;
    int*   idx  = (int*)(g2 + (size_t)n * 64);
    float* pd   = xcat;
    int*   pi   = (int*)(xcat + (size_t)n * 80);

    embed_kernel<<<(n * 192 + 255) / 256, 256, 0, stream>>>(
        node_feat, rf_feat, txp_feat, Wb, bb, Wr, br, Wt, bt, xcat, n);
    fuse_kernel<<<(n * 128 + 255) / 256, 256, 0, stream>>>(xcat, Wf, bf, h, n);

    // layer 1: KNN on h (D=128) + EdgeConv -> g1
    sqnorm_kernel<<<(n * 64 + 255) / 256, 256, 0, stream>>>(h, sqv, n, 128);
    knn_kernel<128><<<(n / 128) * 8, 256, 0, stream>>>(h, sqv, pd, pi, n);
    knn_merge_kernel<<<(n + 255) / 256, 256, 0, stream>>>(pd, pi, idx, n);
    edgeconv_kernel<128><<<n / 4, 64, 0, stream>>>(h, idx, We1, be1, g1, n);

    // layer 2: KNN on g1 (D=64) + EdgeConv -> g2
    sqnorm_kernel<<<(n * 64 + 255) / 256, 256, 0, stream>>>(g1, sqv, n, 64);
    knn_kernel<64><<<(n / 128) * 8, 256, 0, stream>>>(g1, sqv, pd, pi, n);
    knn_merge_kernel<<<(n + 255) / 256, 256, 0, stream>>>(pd, pi, idx, n);
    edgeconv_kernel<64><<<n / 4, 64, 0, stream>>>(g1, idx, We2, be2, g2, n);

    classifier_kernel<<<(n * 16 + 255) / 256, 256, 0, stream>>>(g1, g2, Wc, bc,
                                                                (float*)d_out, n);
}

// Round 6
// 3078.796 us; speedup vs baseline: 2.8642x; 1.1001x over previous
//
#include <hip/hip_runtime.h>
#include <hip/hip_bf16.h>

#define N_NODES 16384
#define KNBR 10

// async global->LDS, 16B per lane; LDS dest must be wave-uniform base (lane*16 implicit)
__device__ __forceinline__ void gload_lds16(const float* g, void* l) {
    __builtin_amdgcn_global_load_lds((const __attribute__((address_space(1))) void*)g,
                                     (__attribute__((address_space(3))) void*)l,
                                     16, 0, 0);
}

// ---------------------------------------------------------------------------
// K1: per-modality embeds -> xcat [N,192]  (ReLU(Linear))
// ---------------------------------------------------------------------------
__global__ __launch_bounds__(256) void embed_kernel(
        const float* __restrict__ nf, const float* __restrict__ rf,
        const float* __restrict__ tf,
        const float* __restrict__ Wb, const float* __restrict__ bb,
        const float* __restrict__ Wr, const float* __restrict__ br,
        const float* __restrict__ Wt, const float* __restrict__ bt,
        float* __restrict__ xcat, int n) {
    int t = blockIdx.x * blockDim.x + threadIdx.x;
    if (t >= n * 192) return;
    int i = t / 192, o = t % 192;
    float acc;
    if (o < 64) {
        acc = bb[o];
        #pragma unroll
        for (int d = 0; d < 8; ++d) acc = fmaf(nf[i * 8 + d], Wb[d * 64 + o], acc);
    } else if (o < 128) {
        int oo = o - 64;
        acc = br[oo];
        #pragma unroll 8
        for (int d = 0; d < 64; ++d) acc = fmaf(rf[i * 64 + d], Wr[d * 64 + oo], acc);
    } else {
        int oo = o - 128;
        acc = bt[oo];
        #pragma unroll 8
        for (int d = 0; d < 64; ++d) acc = fmaf(tf[i * 64 + d], Wt[d * 64 + oo], acc);
    }
    xcat[t] = fmaxf(acc, 0.0f);
}

// ---------------------------------------------------------------------------
// K2: fusion -> h [N,128]  (LeakyReLU(Linear))
// ---------------------------------------------------------------------------
__global__ __launch_bounds__(256) void fuse_kernel(
        const float* __restrict__ xcat, const float* __restrict__ Wf,
        const float* __restrict__ bf, float* __restrict__ h, int n) {
    int t = blockIdx.x * blockDim.x + threadIdx.x;
    if (t >= n * 128) return;
    int i = t >> 7, o = t & 127;
    float acc = bf[o];
    const float* xr = xcat + (size_t)i * 192;
    #pragma unroll 8
    for (int d = 0; d < 192; ++d) acc = fmaf(xr[d], Wf[d * 128 + o], acc);
    h[t] = acc > 0.f ? acc : 0.01f * acc;
}

// ---------------------------------------------------------------------------
// K3: row squared-norms (one wave per row)
// ---------------------------------------------------------------------------
__global__ void sqnorm_kernel(const float* __restrict__ x, float* __restrict__ sq,
                              int n, int D) {
    int w = (blockIdx.x * blockDim.x + threadIdx.x) >> 6;
    int lane = threadIdx.x & 63;
    if (w >= n) return;
    float s = 0.f;
    for (int d = lane; d < D; d += 64) {
        float v = x[(size_t)w * D + d];
        s = fmaf(v, v, s);
    }
    #pragma unroll
    for (int off = 32; off > 0; off >>= 1) s += __shfl_down(s, off);
    if (lane == 0) sq[w] = s;
}

// ---------------------------------------------------------------------------
// K4: fused pairwise-distance GEMM + per-row top-10 over a j-slice.
//   grid = (n/128) * 8 slices; block = 256 threads; tile 128x256; micro 8x16.
//   (R4 post-mortem: 8x8 was LDS-latency-bound at 2 waves/SIMD, VALUBusy 61%.
//    8x16 cuts LDS bytes/FMA 1.0 -> 0.75 and doubles FMA run per bv read.)
//   d staged in KC=32 chunks via global_load_lds (linear LDS dest, source
//   pre-swizzled so compute reads are XOR-deswizzled: av conflict-free
//   16-way bcast, bv 2-way).
//   LDS: union{ XiC[128][8]f4 16KB + XjC[256][8]f4 32KB | Dt[128][65] 33.3KB }
//        + sqj[256] -> 50176 B total.
//   __launch_bounds__(256,2): VGPR budget 256; est. liveness ~216 (acc 128 +
//   av 32 + bd/bi 20 + addr/misc). Spill tripwire: WRITE_SIZE.
//   Scan: thread tid<128 owns query row; strict-< streaming insert in
//   ascending-j order == jax.lax.top_k low-index tie-break. Emits per-slice
//   (dist,idx) top-10 partials, merged by knn_merge_kernel.
// ---------------------------------------------------------------------------
template <int D>
__global__ __launch_bounds__(256, 2) void knn_kernel(const float* __restrict__ x,
                                                     const float* __restrict__ sq,
                                                     float* __restrict__ pd,
                                                     int* __restrict__ pi, int n) {
    constexpr int TM = 128, TJ = 256, KC = 32, LD4 = KC / 4;  // 8 f4 per row-chunk
    constexpr int NCH = D / KC;
    constexpr int PSL = 8;

    __shared__ __align__(16) char smem[49152 + 1024];
    float4* XiC = (float4*)smem;                    // [128][8]
    float4* XjC = ((float4*)smem) + TM * LD4;       // [256][8]
    float*  Dt  = (float*)smem;                     // [128][65]  (union)
    float*  sqj = (float*)(smem + 49152);           // [256]

    const int tid  = threadIdx.x;
    const int wv   = tid >> 6;
    const int lane = tid & 63;
    const int ty = tid >> 4, tx = tid & 15;          // ty 0..15, tx 0..15
    const int mb = blockIdx.x >> 3, ps = blockIdx.x & 7;
    const int i0 = mb * TM;
    const int jsl = n >> 3;                 // 2048 cols per slice
    const int j0 = ps * jsl;

    // staging geometry: Xi 1024 f4 in 4 wave-issues, Xj 2048 f4 in 8.
    // LDS slot (row, fi&7) receives global f4 column (fi&7)^(row&7).
    int offI[4], offJ[8];
    #pragma unroll
    for (int w = 0; w < 4; ++w) {
        int fi = (wv * 4 + w) * 64 + lane;
        int row = fi >> 3, col = (fi & 7) ^ (row & 7);
        offI[w] = (i0 + row) * D + col * 4;
    }
    #pragma unroll
    for (int w = 0; w < 8; ++w) {
        int fi = (wv * 8 + w) * 64 + lane;
        int row = fi >> 3, col = (fi & 7) ^ (row & 7);
        offJ[w] = (j0 + row) * D + col * 4;
    }

    float bd[KNBR];
    int bi[KNBR];
    #pragma unroll
    for (int q = 0; q < KNBR; ++q) { bd[q] = 3.4e38f; bi[q] = 0; }
    const float my_sqi = (tid < TM) ? sq[i0 + tid] : 0.f;

    for (int jt = 0; jt < jsl; jt += TJ) {
        float acc[8][16];
        #pragma unroll
        for (int r = 0; r < 8; ++r)
            #pragma unroll
            for (int c = 0; c < 16; ++c) acc[r][c] = 0.f;

        for (int s = 0; s < NCH; ++s) {
            __syncthreads();  // prev scan / prev chunk compute done -> LDS reusable
            #pragma unroll
            for (int w = 0; w < 4; ++w)
                gload_lds16(x + offI[w] + s * KC, XiC + (wv * 4 + w) * 64);
            #pragma unroll
            for (int w = 0; w < 8; ++w)
                gload_lds16(x + offJ[w] + jt * D + s * KC, XjC + (wv * 8 + w) * 64);
            if (s == 0) sqj[tid] = sq[j0 + jt + tid];
            __syncthreads();  // barrier drains vmcnt -> staged data visible

            #pragma unroll 2
            for (int d4 = 0; d4 < LD4; ++d4) {
                const int si = d4 ^ (ty & 7);   // rows ty+16r share (row&7)=ty&7
                const int sj = d4 ^ (tx & 7);
                float4 av[8];
                #pragma unroll
                for (int r = 0; r < 8; ++r) av[r] = XiC[(ty + 16 * r) * LD4 + si];
                #pragma unroll
                for (int c = 0; c < 16; ++c) {
                    float4 bv = XjC[(tx + 16 * c) * LD4 + sj];
                    #pragma unroll
                    for (int r = 0; r < 8; ++r) {
                        acc[r][c] = fmaf(av[r].x, bv.x, acc[r][c]);
                        acc[r][c] = fmaf(av[r].y, bv.y, acc[r][c]);
                        acc[r][c] = fmaf(av[r].z, bv.z, acc[r][c]);
                        acc[r][c] = fmaf(av[r].w, bv.w, acc[r][c]);
                    }
                }
            }
        }

        // dump + scan in four 64-col quarters (Dt unioned over XiC/XjC)
        #pragma unroll
        for (int h = 0; h < 4; ++h) {
            __syncthreads();  // h=0: compute reads done; else: prev quarter scan done
            #pragma unroll
            for (int r = 0; r < 8; ++r)
                #pragma unroll
                for (int cc = 0; cc < 4; ++cc)
                    Dt[(ty + 16 * r) * 65 + tx + 16 * cc] = acc[r][4 * h + cc];
            __syncthreads();
            if (tid < TM) {
                const int ig = i0 + tid;
                const float* drow = Dt + tid * 65;
                const int jb = j0 + jt + 64 * h;
                for (int c2 = 0; c2 < 64; ++c2) {
                    int j = jb + c2;
                    float dist = my_sqi + sqj[64 * h + c2] - 2.0f * drow[c2];
                    if (dist < bd[KNBR - 1] && j != ig) {
                        bd[KNBR - 1] = dist;
                        bi[KNBR - 1] = j;
                        #pragma unroll
                        for (int q2 = KNBR - 2; q2 >= 0; --q2) {
                            if (bd[q2 + 1] < bd[q2]) {
                                float td = bd[q2]; bd[q2] = bd[q2 + 1]; bd[q2 + 1] = td;
                                int tj = bi[q2]; bi[q2] = bi[q2 + 1]; bi[q2 + 1] = tj;
                            }
                        }
                    }
                }
            }
        }
    }

    if (tid < TM) {
        size_t base = ((size_t)(i0 + tid) * PSL + ps) * KNBR;
        #pragma unroll
        for (int q = 0; q < KNBR; ++q) { pd[base + q] = bd[q]; pi[base + q] = bi[q]; }
    }
}

// ---------------------------------------------------------------------------
// K4b: merge 8 per-slice sorted top-10 partials -> final top-10 indices.
//   Slices processed in ascending-j order with strict-< insert => stable
//   low-index tie-break preserved globally.
// ---------------------------------------------------------------------------
__global__ __launch_bounds__(256) void knn_merge_kernel(const float* __restrict__ pd,
                                                        const int* __restrict__ pi,
                                                        int* __restrict__ idx, int n) {
    int row = blockIdx.x * blockDim.x + threadIdx.x;
    if (row >= n) return;
    float bd[KNBR];
    int bi[KNBR];
    #pragma unroll
    for (int q = 0; q < KNBR; ++q) { bd[q] = 3.4e38f; bi[q] = 0; }
    const float* prow = pd + (size_t)row * 8 * KNBR;
    const int*   irow = pi + (size_t)row * 8 * KNBR;
    for (int e = 0; e < 8 * KNBR; ++e) {
        float dist = prow[e];
        if (dist < bd[KNBR - 1]) {
            bd[KNBR - 1] = dist;
            bi[KNBR - 1] = irow[e];
            #pragma unroll
            for (int q2 = KNBR - 2; q2 >= 0; --q2) {
                if (bd[q2 + 1] < bd[q2]) {
                    float td = bd[q2]; bd[q2] = bd[q2 + 1]; bd[q2 + 1] = td;
                    int tj = bi[q2]; bi[q2] = bi[q2 + 1]; bi[q2 + 1] = tj;
                }
            }
        }
    }
    #pragma unroll
    for (int q = 0; q < KNBR; ++q) idx[(size_t)row * KNBR + q] = bi[q];
}

// ---------------------------------------------------------------------------
// K5: EdgeConv: out[i,o] = max_k leaky_relu( [x_i, x_j-x_i] @ W + b )
//   structure split: a_o = b_o + x_i . W_top[:,o] computed once per node.
//   R4 post-mortem: 64-thread blocks gave only 7 waves/CU (latency-exposed).
//   Now: 256-thread blocks = 4 waves, wave wv owns node base+wv (28 waves/CU).
//   xi/xd staged in LDS as float4; inner reads are same-address broadcast
//   ds_read_b128 (conflict-free), 4 d-values per read.
// ---------------------------------------------------------------------------
template <int D>
__global__ __launch_bounds__(256) void edgeconv_kernel(const float* __restrict__ x,
                                                       const int* __restrict__ idx,
                                                       const float* __restrict__ W,
                                                       const float* __restrict__ bias,
                                                       float* __restrict__ out, int n) {
    constexpr int D4 = D / 4;
    const int wv = threadIdx.x >> 6;       // wave = node within block
    const int o  = threadIdx.x & 63;       // output channel
    const int node = blockIdx.x * 4 + wv;

    __shared__ float4 xi4[4][D4];
    __shared__ float4 xd4[4][KNBR][D4];

    float4 xif = make_float4(0.f, 0.f, 0.f, 0.f);
    if (o < D4) {
        xif = *reinterpret_cast<const float4*>(x + (size_t)node * D + o * 4);
        xi4[wv][o] = xif;
    }
    for (int k = 0; k < KNBR; ++k) {
        int j = idx[(size_t)node * KNBR + k];   // wave-uniform broadcast load
        if (o < D4) {
            float4 xj = *reinterpret_cast<const float4*>(x + (size_t)j * D + o * 4);
            xd4[wv][k][o] = make_float4(xj.x - xif.x, xj.y - xif.y,
                                        xj.z - xif.z, xj.w - xif.w);
        }
    }
    __syncthreads();

    // a = bias + x_i . W_top[:,o]
    float a = bias[o];
    for (int d4 = 0; d4 < D4; ++d4) {
        float4 xv = xi4[wv][d4];  // broadcast read
        a = fmaf(xv.x, W[(d4 * 4 + 0) * 64 + o], a);
        a = fmaf(xv.y, W[(d4 * 4 + 1) * 64 + o], a);
        a = fmaf(xv.z, W[(d4 * 4 + 2) * 64 + o], a);
        a = fmaf(xv.w, W[(d4 * 4 + 3) * 64 + o], a);
    }

    float m = -3.4e38f;
    for (int k = 0; k < KNBR; ++k) {
        float acc = a;
        for (int d4 = 0; d4 < D4; ++d4) {
            float4 xv = xd4[wv][k][d4];  // broadcast read
            acc = fmaf(xv.x, W[(D + d4 * 4 + 0) * 64 + o], acc);
            acc = fmaf(xv.y, W[(D + d4 * 4 + 1) * 64 + o], acc);
            acc = fmaf(xv.z, W[(D + d4 * 4 + 2) * 64 + o], acc);
            acc = fmaf(xv.w, W[(D + d4 * 4 + 3) * 64 + o], acc);
        }
        float v = acc > 0.f ? acc : 0.01f * acc;
        m = fmaxf(m, v);
    }
    out[(size_t)node * 64 + o] = m;
}

// ---------------------------------------------------------------------------
// K6: classifier logits = [g1,g2] @ Wc + bc
// ---------------------------------------------------------------------------
__global__ void classifier_kernel(const float* __restrict__ g1, const float* __restrict__ g2,
                                  const float* __restrict__ Wc, const float* __restrict__ bc,
                                  float* __restrict__ out, int n) {
    int t = blockIdx.x * blockDim.x + threadIdx.x;
    if (t >= n * 16) return;
    int i = t >> 4, c = t & 15;
    float acc = bc[c];
    #pragma unroll 8
    for (int d = 0; d < 64; ++d) acc = fmaf(g1[(size_t)i * 64 + d], Wc[d * 16 + c], acc);
    #pragma unroll 8
    for (int d = 0; d < 64; ++d) acc = fmaf(g2[(size_t)i * 64 + d], Wc[(64 + d) * 16 + c], acc);
    out[t] = acc;
}

// ---------------------------------------------------------------------------
extern "C" void kernel_launch(void* const* d_in, const int* in_sizes, int n_in,
                              void* d_out, int out_size, void* d_ws, size_t ws_size,
                              hipStream_t stream) {
    const int n = N_NODES;
    const float* node_feat = (const float*)d_in[0];
    const float* rf_feat   = (const float*)d_in[1];
    const float* txp_feat  = (const float*)d_in[2];
    const float* Wb = (const float*)d_in[3];
    const float* bb = (const float*)d_in[4];
    const float* Wr = (const float*)d_in[5];
    const float* br = (const float*)d_in[6];
    const float* Wt = (const float*)d_in[7];
    const float* bt = (const float*)d_in[8];
    const float* Wf = (const float*)d_in[9];
    const float* bf = (const float*)d_in[10];
    const float* We1 = (const float*)d_in[11];
    const float* be1 = (const float*)d_in[12];
    const float* We2 = (const float*)d_in[13];
    const float* be2 = (const float*)d_in[14];
    const float* Wc = (const float*)d_in[15];
    const float* bc = (const float*)d_in[16];

    // workspace layout (fp32): xcat | h | sq | g1 | g2 | idx
    // knn partials (pd/pi: n*80 floats/ints each = n*160 < n*192) alias xcat,
    // which is dead after fuse_kernel.
    float* xcat = (float*)d_ws;
    float* h    = xcat + (size_t)n * 192;
    float* sqv  = h + (size_t)n * 128;
    float* g1   = sqv + n;
    float* g2   = g1 + (size_t)n * 64;
    int*   idx  = (int*)(g2 + (size_t)n * 64);
    float* pd   = xcat;
    int*   pi   = (int*)(xcat + (size_t)n * 80);

    embed_kernel<<<(n * 192 + 255) / 256, 256, 0, stream>>>(
        node_feat, rf_feat, txp_feat, Wb, bb, Wr, br, Wt, bt, xcat, n);
    fuse_kernel<<<(n * 128 + 255) / 256, 256, 0, stream>>>(xcat, Wf, bf, h, n);

    // layer 1: KNN on h (D=128) + EdgeConv -> g1
    sqnorm_kernel<<<(n * 64 + 255) / 256, 256, 0, stream>>>(h, sqv, n, 128);
    knn_kernel<128><<<(n / 128) * 8, 256, 0, stream>>>(h, sqv, pd, pi, n);
    knn_merge_kernel<<<(n + 255) / 256, 256, 0, stream>>>(pd, pi, idx, n);
    edgeconv_kernel<128><<<n / 4, 256, 0, stream>>>(h, idx, We1, be1, g1, n);

    // layer 2: KNN on g1 (D=64) + EdgeConv -> g2
    sqnorm_kernel<<<(n * 64 + 255) / 256, 256, 0, stream>>>(g1, sqv, n, 64);
    knn_kernel<64><<<(n / 128) * 8, 256, 0, stream>>>(g1, sqv, pd, pi, n);
    knn_merge_kernel<<<(n + 255) / 256, 256, 0, stream>>>(pd, pi, idx, n);
    edgeconv_kernel<64><<<n / 4, 256, 0, stream>>>(g1, idx, We2, be2, g2, n);

    classifier_kernel<<<(n * 16 + 255) / 256, 256, 0, stream>>>(g1, g2, Wc, bc,
                                                                (float*)d_out, n);
}